// Round 1
// baseline (493.035 us; speedup 1.0000x reference)
//
#include <hip/hip_runtime.h>
#include <math.h>

#define BB 8
#define PP 57744
#define NOBJ 20
#define CC 81
#define ROWS (BB*PP)
#define CPB 16        // rows per block in k_conf (16 lanes per row)
#define BPSPLIT 16    // prior-scan splits in k_best_prior
#define BPCHUNK ((PP + BPSPLIT - 1) / BPSPLIT)   // 3609

// ws layout in 4-byte units
#define W_CNT  0      // [0]=num_pos [1]=sl1_sum [2]=pos_ce [3]=neg_ce [4]=neg_cnt [5]=eqCtr [8]=prefix [9]=Kr [10]=T [11]=eqSlots
#define W_HIST 64     // 4*256 bins
#define W_BP   1088   // 160 u64 (byte offset 4352, 8-aligned)
#define W_CONF 2048           // ROWS ints
#define W_KEY  (2048 + ROWS)  // ROWS uints
#define W_CE   (2048 + 2*ROWS)// ROWS floats

__device__ __forceinline__ unsigned keymap(float f) {
    unsigned u = __float_as_uint(f);
    return (u & 0x80000000u) ? ~u : (u | 0x80000000u);
}

__device__ __forceinline__ float smooth_l1(float d) {
    float a = fabsf(d);
    return a < 1.f ? 0.5f * d * d : a - 0.5f;
}

// Grid (NOBJ, BB, BPSPLIT): per-(gt,batch) argmax over a prior chunk, packed
// (iou_bits<<32)|(~p) so u64 max == (max iou, lowest prior idx). IoU >= 0 so
// raw float bits are order-preserving.
__global__ void k_best_prior(const float* __restrict__ priors,
                             const float* __restrict__ gt,
                             unsigned long long* __restrict__ bp) {
    int n = blockIdx.x, b = blockIdx.y;
    int p0 = blockIdx.z * BPCHUNK;
    int p1 = min(p0 + BPCHUNK, PP);
    const float* t = gt + (b * NOBJ + n) * 4;
    float tx1 = t[0], ty1 = t[1], tx2 = t[2], ty2 = t[3];
    float ta = (tx2 - tx1) * (ty2 - ty1);
    unsigned long long best = 0ull;
    for (int p = p0 + threadIdx.x; p < p1; p += 256) {
        float4 pr = ((const float4*)priors)[p];
        float px1 = pr.x - pr.z * 0.5f, py1 = pr.y - pr.w * 0.5f;
        float px2 = pr.x + pr.z * 0.5f, py2 = pr.y + pr.w * 0.5f;
        float iw = fmaxf(fminf(tx2, px2) - fmaxf(tx1, px1), 0.f);
        float ih = fmaxf(fminf(ty2, py2) - fmaxf(ty1, py1), 0.f);
        float inter = iw * ih;
        float iou = inter / (ta + (px2 - px1) * (py2 - py1) - inter);
        unsigned long long pk = ((unsigned long long)__float_as_uint(iou) << 32)
                              | (unsigned long long)(0xFFFFFFFFu - (unsigned)p);
        if (pk > best) best = pk;
    }
    __shared__ unsigned long long sb[256];
    int tid = threadIdx.x;
    sb[tid] = best; __syncthreads();
    for (int s = 128; s > 0; s >>= 1) {
        if (tid < s && sb[tid + s] > sb[tid]) sb[tid] = sb[tid + s];
        __syncthreads();
    }
    if (tid == 0) atomicMax(&bp[b * NOBJ + n], sb[0]);
}

// Per prior: best truth (argmax over 20, tie->first), force-match (last gt wins),
// conf_t, and smooth-L1 loc loss for positives.
__global__ void k_match(const float* __restrict__ loc_data,
                        const float* __restrict__ priors,
                        const float* __restrict__ gt,
                        const int* __restrict__ labels,
                        const unsigned long long* __restrict__ bp,
                        int* __restrict__ conf_t,
                        float* __restrict__ cnt_f,
                        int* __restrict__ cnt_i) {
    int b = blockIdx.y;
    int tid = threadIdx.x;
    int p = blockIdx.x * 256 + tid;
    __shared__ float st[NOBJ][4];
    __shared__ int slab[NOBJ], sbp[NOBJ];
    if (tid < NOBJ * 4) ((float*)st)[tid] = gt[b * NOBJ * 4 + tid];
    if (tid < NOBJ) {
        slab[tid] = labels[b * NOBJ + tid];
        sbp[tid] = (int)(0xFFFFFFFFu - (unsigned)bp[b * NOBJ + tid]);
    }
    __syncthreads();
    float s_l1 = 0.f; int is_pos = 0;
    if (p < PP) {
        float4 pr = ((const float4*)priors)[p];
        float px1 = pr.x - pr.z * 0.5f, py1 = pr.y - pr.w * 0.5f;
        float px2 = pr.x + pr.z * 0.5f, py2 = pr.y + pr.w * 0.5f;
        float pa = (px2 - px1) * (py2 - py1);
        float best = -1.f; int bn = 0;
        for (int n = 0; n < NOBJ; n++) {
            float tx1 = st[n][0], ty1 = st[n][1], tx2 = st[n][2], ty2 = st[n][3];
            float iw = fmaxf(fminf(tx2, px2) - fmaxf(tx1, px1), 0.f);
            float ih = fmaxf(fminf(ty2, py2) - fmaxf(ty1, py1), 0.f);
            float inter = iw * ih;
            float iou = inter / ((tx2 - tx1) * (ty2 - ty1) + pa - inter);
            if (iou > best) { best = iou; bn = n; }  // tie -> first n
        }
        float ov = best;
        for (int n = 0; n < NOBJ; n++)
            if (sbp[n] == p) { bn = n; ov = 2.0f; }  // last n wins
        int conf = slab[bn];
        if (ov < 0.5f) conf = -1;
        if (ov < 0.4f) conf = 0;
        conf_t[b * PP + p] = conf;
        if (conf > 0) {
            is_pos = 1;
            float mx1 = st[bn][0], my1 = st[bn][1], mx2 = st[bn][2], my2 = st[bn][3];
            float gcx = ((mx1 + mx2) * 0.5f - pr.x) / (0.1f * pr.z);
            float gcy = ((my1 + my2) * 0.5f - pr.y) / (0.1f * pr.w);
            float gw = logf((mx2 - mx1) / pr.z) / 0.2f;
            float gh = logf((my2 - my1) / pr.w) / 0.2f;
            float4 ld = ((const float4*)loc_data)[b * PP + p];
            s_l1 = smooth_l1(ld.x - gcx) + smooth_l1(ld.y - gcy) +
                   smooth_l1(ld.z - gw) + smooth_l1(ld.w - gh);
        }
    }
    __shared__ float rs[256]; __shared__ int rc[256];
    rs[tid] = s_l1; rc[tid] = is_pos; __syncthreads();
    for (int s = 128; s > 0; s >>= 1) {
        if (tid < s) { rs[tid] += rs[tid + s]; rc[tid] += rc[tid + s]; }
        __syncthreads();
    }
    if (tid == 0) {
        if (rs[0] != 0.f) atomicAdd(&cnt_f[1], rs[0]);
        if (rc[0])        atomicAdd(&cnt_i[0], rc[0]);
    }
}

// Softmax CE + fg-score key per row, 16 lanes per row, all in registers.
// Lane t holds classes {t, t+16, t+32, t+48, t+64} (always valid since
// t+64 <= 79 < 81) plus class 80 on lane t==0. No LDS, no barriers:
// 6 independent loads in flight per lane-group, butterfly reductions
// via __shfl_xor within the 16-lane group.
__global__ void __launch_bounds__(256, 8)
k_conf(const float* __restrict__ conf_data,
       const int* __restrict__ conf_t,
       unsigned* __restrict__ key,
       float* __restrict__ ce,
       float* __restrict__ cnt_f) {
    int tid = threadIdx.x;
    int t = tid & 15;
    int row = blockIdx.x * CPB + (tid >> 4);
    const float* x = conf_data + (size_t)row * CC;

    float a0 = x[t];
    float a1 = x[t + 16];
    float a2 = x[t + 32];
    float a3 = x[t + 48];
    float a4 = x[t + 64];
    float a5 = -INFINITY;
    if (t == 0) a5 = x[80];
    int ct = conf_t[row];   // same addr across the 16-lane group (broadcast)

    // fg = max over classes [1, 80]
    float fg = fmaxf(fmaxf(fmaxf(a1, a2), fmaxf(a3, a4)), a5);
    if (t != 0) fg = fmaxf(fg, a0);
    fg = fmaxf(fg, __shfl_xor(fg, 1));
    fg = fmaxf(fg, __shfl_xor(fg, 2));
    fg = fmaxf(fg, __shfl_xor(fg, 4));
    fg = fmaxf(fg, __shfl_xor(fg, 8));
    // m = max over all classes = max(fg, x[0]); x[0] lives on group lane 0
    float x0 = __shfl(a0, tid & 48);
    float m = fmaxf(fg, x0);

    const float LOG2E = 1.4426950408889634f;
    float e = exp2f((a0 - m) * LOG2E) + exp2f((a1 - m) * LOG2E)
            + exp2f((a2 - m) * LOG2E) + exp2f((a3 - m) * LOG2E)
            + exp2f((a4 - m) * LOG2E) + exp2f((a5 - m) * LOG2E);
    e += __shfl_xor(e, 1);
    e += __shfl_xor(e, 2);
    e += __shfl_xor(e, 4);
    e += __shfl_xor(e, 8);

    // fetch x[ctc]: group-uniform register select + one shuffle
    int ctc = min(max(ct, 0), CC - 1);
    int kk = ctc >> 4;
    float sel = (kk == 0) ? a0 : (kk == 1) ? a1 : (kk == 2) ? a2
              : (kk == 3) ? a3 : (kk == 4) ? a4 : a5;
    float xc = __shfl(sel, (tid & 48) | (ctc & 15));

    if (t == 0) {
        float lse = m + log2f(e) * 0.6931471805599453f;
        float cev = lse - xc;
        ce[row] = cev;
        key[row] = (ct == 0) ? keymap(fg) : 0u;
        if (ct > 0) atomicAdd(&cnt_f[2], cev);
    }
}

// Radix-select pass s (8-bit digits, MSB first) histogram.
__global__ void k_hist(const unsigned* __restrict__ key,
                       unsigned* __restrict__ hist,
                       const int* __restrict__ cnt, int s) {
    __shared__ unsigned lh[256];
    int tid = threadIdx.x;
    lh[tid] = 0; __syncthreads();
    unsigned prefix = (s == 0) ? 0u : (unsigned)cnt[8];
    int shift = 24 - 8 * s;
    for (int r = blockIdx.x * 256 + tid; r < ROWS; r += gridDim.x * 256) {
        unsigned k = key[r];
        if (s == 0 || (k >> (shift + 8)) == prefix)
            atomicAdd(&lh[(k >> shift) & 0xffu], 1u);
    }
    __syncthreads();
    if (lh[tid]) atomicAdd(&hist[s * 256 + tid], lh[tid]);
}

// Pick the digit where the descending cumulative count crosses Kr.
__global__ void k_scan(const unsigned* __restrict__ hist, int* __restrict__ cnt, int s) {
    __shared__ unsigned sd[256];
    int i = threadIdx.x;
    sd[i] = hist[s * 256 + i];
    __syncthreads();
    for (int off = 1; off < 256; off <<= 1) {
        unsigned add = (i + off < 256) ? sd[i + off] : 0u;
        __syncthreads();
        sd[i] += add;
        __syncthreads();
    }
    unsigned Kr, prefix;
    if (s == 0) { Kr = 3u * (unsigned)cnt[0]; prefix = 0u; }
    else        { prefix = (unsigned)cnt[8]; Kr = (unsigned)cnt[9]; }
    unsigned cum = sd[i];
    unsigned upper = (i < 255) ? sd[i + 1] : 0u;
    bool sel = (upper < Kr) && (cum >= Kr || i == 0);
    if (sel) {
        unsigned np = (prefix << 8) | (unsigned)i;
        unsigned nKr = Kr - upper;
        if (s < 3) { cnt[8] = (int)np; cnt[9] = (int)nKr; }
        else       { cnt[10] = (int)np; cnt[11] = (int)nKr; }
    }
}

// Sum CE over selected negatives (key > T, or == T up to eqSlots).
__global__ void k_negsum(const unsigned* __restrict__ key,
                         const float* __restrict__ ce,
                         const int* __restrict__ conf_t,
                         int* __restrict__ cnt_i,
                         float* __restrict__ cnt_f) {
    int tid = threadIdx.x;
    int r = blockIdx.x * 256 + tid;
    float s = 0.f; int c = 0;
    unsigned T = (unsigned)cnt_i[10];
    int eqS = cnt_i[11];
    if (r < ROWS && conf_t[r] == 0) {
        unsigned k = key[r];
        bool sel = false;
        if (k > T) sel = true;
        else if (k == T) { int slot = atomicAdd(&cnt_i[5], 1); sel = slot < eqS; }
        if (sel) { s = ce[r]; c = 1; }
    }
    __shared__ float rs[256]; __shared__ int rc[256];
    rs[tid] = s; rc[tid] = c; __syncthreads();
    for (int st = 128; st > 0; st >>= 1) {
        if (tid < st) { rs[tid] += rs[tid + st]; rc[tid] += rc[tid + st]; }
        __syncthreads();
    }
    if (tid == 0) {
        if (rs[0] != 0.f) atomicAdd(&cnt_f[3], rs[0]);
        if (rc[0])        atomicAdd(&cnt_i[4], rc[0]);
    }
}

__global__ void k_final(const int* __restrict__ cnt_i,
                        const float* __restrict__ cnt_f,
                        float* __restrict__ out) {
    int np = cnt_i[0], nn = cnt_i[4];
    out[0] = cnt_f[1] / (float)max(np, 1);
    out[1] = (cnt_f[2] + cnt_f[3]) / (float)max(np + nn, 1);
}

extern "C" void kernel_launch(void* const* d_in, const int* in_sizes, int n_in,
                              void* d_out, int out_size, void* d_ws, size_t ws_size,
                              hipStream_t stream) {
    const float* loc    = (const float*)d_in[0];
    const float* conf   = (const float*)d_in[1];
    const float* priors = (const float*)d_in[2];
    const float* gt     = (const float*)d_in[3];
    const int*   labels = (const int*)d_in[4];
    float* out = (float*)d_out;
    int*      wi = (int*)d_ws;
    float*    wf = (float*)d_ws;
    unsigned* wu = (unsigned*)d_ws;
    unsigned long long* wbp = (unsigned long long*)(wi + W_BP);

    hipMemsetAsync(d_ws, 0, 8192, stream);  // counters + hists + bp
    k_best_prior<<<dim3(NOBJ, BB, BPSPLIT), 256, 0, stream>>>(priors, gt, wbp);
    k_match<<<dim3((PP + 255) / 256, BB), 256, 0, stream>>>(
        loc, priors, gt, labels, wbp, wi + W_CONF, wf, wi);
    k_conf<<<ROWS / CPB, 256, 0, stream>>>(conf, wi + W_CONF, wu + W_KEY, wf + W_CE, wf);
    for (int s = 0; s < 4; s++) {
        k_hist<<<512, 256, 0, stream>>>(wu + W_KEY, wu + W_HIST, wi, s);
        k_scan<<<1, 256, 0, stream>>>(wu + W_HIST, wi, s);
    }
    k_negsum<<<(ROWS + 255) / 256, 256, 0, stream>>>(
        wu + W_KEY, wf + W_CE, wi + W_CONF, wi, wf);
    k_final<<<1, 1, 0, stream>>>(wi, wf, out);
}